// Round 6
// baseline (369.736 us; speedup 1.0000x reference)
//
#include <hip/hip_runtime.h>

typedef __bf16 bf16;
typedef __bf16 v8bf __attribute__((ext_vector_type(8)));
typedef __bf16 v4bf __attribute__((ext_vector_type(4)));
typedef float  v4f  __attribute__((ext_vector_type(4)));

__device__ __forceinline__ void gload_lds16(const void* g, void* l) {
    __builtin_amdgcn_global_load_lds(
        (const __attribute__((address_space(1))) void*)g,
        (__attribute__((address_space(3))) void*)l, 16, 0, 0);
}

#define MFMA16(a, b, c) __builtin_amdgcn_mfma_f32_16x16x32_bf16((a), (b), (c), 0, 0, 0)

// ---------------------------------------------------------------------------
// Kernel 1: LayerNorm over D=768 + bf16 casts. One block per row, 256 thr.
// Blocks 0..63 also zero the softmax row-sum accumulator L (16384 floats).
// ---------------------------------------------------------------------------
__global__ __launch_bounds__(256)
void ln_cast(const float* __restrict__ x, const float* __restrict__ g,
             const float* __restrict__ b, bf16* __restrict__ xn,
             bf16* __restrict__ xv, float* __restrict__ L)
{
    const long row = blockIdx.x;
    const float* xr = x + row * 768;
    const int tid = threadIdx.x;
    const int wave = tid >> 6, lane = tid & 63;

    if (row < 64) L[row * 256 + tid] = 0.0f;

    float a0 = xr[tid], a1 = xr[tid + 256], a2 = xr[tid + 512];
    float s = a0 + a1 + a2;
    #pragma unroll
    for (int off = 32; off; off >>= 1) s += __shfl_xor(s, off);
    __shared__ float sh[4], sh2[4];
    if (!lane) sh[wave] = s;
    __syncthreads();
    const float mu = (sh[0] + sh[1] + sh[2] + sh[3]) * (1.0f / 768.0f);

    float d0 = a0 - mu, d1 = a1 - mu, d2 = a2 - mu;
    float ss = d0 * d0 + d1 * d1 + d2 * d2;
    #pragma unroll
    for (int off = 32; off; off >>= 1) ss += __shfl_xor(ss, off);
    if (!lane) sh2[wave] = ss;
    __syncthreads();
    const float var = (sh2[0] + sh2[1] + sh2[2] + sh2[3]) * (1.0f / 768.0f);
    const float rstd = rsqrtf(var + 1e-5f);

    bf16* xnr = xn + row * 768;
    bf16* xvr = xv + row * 768;
    xnr[tid]       = (bf16)(d0 * rstd * g[tid]       + b[tid]);
    xnr[tid + 256] = (bf16)(d1 * rstd * g[tid + 256] + b[tid + 256]);
    xnr[tid + 512] = (bf16)(d2 * rstd * g[tid + 512] + b[tid + 512]);
    xvr[tid]       = (bf16)a0;
    xvr[tid + 256] = (bf16)a1;
    xvr[tid + 512] = (bf16)a2;
}

// ---------------------------------------------------------------------------
// Kernel 2: weight fp32 -> bf16 convert into Wcat halves. grid (576,2).
// ---------------------------------------------------------------------------
__global__ __launch_bounds__(256)
void cvt_w(const float* __restrict__ Wq, const float* __restrict__ Wk,
           bf16* __restrict__ Wcat)
{
    const int z = blockIdx.y;
    const float* src = z ? Wk : Wq;
    bf16* dst = Wcat + (long)z * 768 * 768;
    const int i = (blockIdx.x * 256 + threadIdx.x) * 4;
    const float4 v = *(const float4*)(src + i);
    v4bf o = {(bf16)v.x, (bf16)v.y, (bf16)v.z, (bf16)v.w};
    *(v4bf*)(dst + i) = o;
}

// ---------------------------------------------------------------------------
// Kernel 2b: 64x64-tile bf16 transpose, XOR-swizzled LDS (conflict-free).
// in: [B][2048][768] -> outT: [B][768][2048]. grid (32, 12, 8), 256 thr.
// ---------------------------------------------------------------------------
__global__ __launch_bounds__(256)
void transpose_bf(const bf16* __restrict__ in, bf16* __restrict__ outT)
{
    __shared__ __attribute__((aligned(16))) bf16 tile[64 * 64];
    const int t0 = blockIdx.x * 64, d0 = blockIdx.y * 64;
    in   += (long)blockIdx.z * 2048 * 768;
    outT += (long)blockIdx.z * 768 * 2048;
    const int tid = threadIdx.x;

    #pragma unroll
    for (int it = 0; it < 2; ++it) {
        const int lin = it * 256 + tid;
        const int r = lin >> 3;
        const int g = lin & 7;
        const int pg = g ^ (r & 7) ^ ((r >> 3) & 7);
        v8bf v = *(const v8bf*)(in + (long)(t0 + r) * 768 + d0 + g * 8);
        *(v8bf*)(tile + r * 64 + pg * 8) = v;
    }
    __syncthreads();
    #pragma unroll
    for (int it = 0; it < 2; ++it) {
        const int lin = it * 256 + tid;
        const int dd = lin >> 3;
        const int tb = lin & 7;
        v8bf o;
        #pragma unroll
        for (int j = 0; j < 8; ++j) {
            const int t = tb * 8 + j;
            const int pg = (dd >> 3) ^ (t & 7) ^ ((t >> 3) & 7);
            o[j] = tile[t * 64 + pg * 8 + (dd & 7)];
        }
        *(v8bf*)(outT + (long)(d0 + dd) * 2048 + t0 + tb * 8) = o;
    }
}

// ---------------------------------------------------------------------------
// Kernel 3: merged Q/K projection, R5 template. A=xn [16384,768],
// W=Wcat [1536,768]. 128(M)x384(N) tile, BK=64, dbuf 2x64KB, 4 barriers per
// K-tile, read-one-phase-ahead, counted vmcnt ledger (1/-/1/3).
// grid 512 = 2 full rounds. XCD chunking: wg=(bx&7)*64+(bx>>3).
// ---------------------------------------------------------------------------
__global__ __launch_bounds__(512, 2)
void gemm_qk(const bf16* __restrict__ A, const bf16* __restrict__ W,
             const float* __restrict__ bq, const float* __restrict__ bk,
             float qscale, bf16* __restrict__ Qb, bf16* __restrict__ Kb)
{
    __shared__ __attribute__((aligned(16))) bf16 lds[2][32768];  // 2 x 64 KB

    const int bx = blockIdx.x;
    const int wg = (bx & 7) * 64 + (bx >> 3);   // XCD-contiguous
    const int m0 = (wg >> 2) * 128;             // 0..16256
    const int n0 = (wg & 3) * 384;              // 0,384,768,1152

    const bf16* Ag = A + (long)m0 * 768;
    const bf16* Bg = W + (long)n0 * 768;

    const int tid = threadIdx.x, wv = tid >> 6, lane = tid & 63;
    const int wr = wv >> 2, wc = wv & 3;
    const int lr = lane & 15, lq = lane >> 4;

    auto stA = [&](int bi, int h, int kk) {            // 1 instr/wave, 8 KB half
        const int lin = wv * 64 + lane;                // 0..511
        const int r = lin >> 3, ck = (lin & 7) ^ (r & 7);
        gload_lds16(Ag + (long)(h * 64 + r) * 768 + kk + ck * 8,
                    (char*)lds + bi * 65536 + h * 8192 + lin * 16);
    };
    auto stB = [&](int bi, int h, int p, int kk) {     // 3 instr/wave, 24 KB half
        const int lin = (wv * 3 + p) * 64 + lane;      // 0..1535
        const int r = lin >> 3, ck = (lin & 7) ^ (r & 7);
        gload_lds16(Bg + (long)(h * 192 + r) * 768 + kk + ck * 8,
                    (char*)lds + bi * 65536 + 16384 + h * 24576 + lin * 16);
    };

    v8bf aS1[2][2], aS2[2][2], aS3[2][2], bS4[3][2], bS5[3][2];
    v4f acc[2][2][2][3] = {};   // [mh][nh][i][n]

    auto rdA = [&](v8bf (&d)[2][2], const bf16* Ls, int mh) {
        #pragma unroll
        for (int i = 0; i < 2; ++i) {
            const int r = mh * 64 + wr * 32 + i * 16 + lr;
            #pragma unroll
            for (int s = 0; s < 2; ++s)
                d[i][s] = *(const v8bf*)(Ls + r * 64 + (((s * 4 + lq) ^ (r & 7)) << 3));
        }
    };
    auto rdB = [&](v8bf (&d)[3][2], const bf16* Ls, int nh) {
        #pragma unroll
        for (int n = 0; n < 3; ++n) {
            const int r = nh * 192 + wc * 48 + n * 16 + lr;
            #pragma unroll
            for (int s = 0; s < 2; ++s)
                d[n][s] = *(const v8bf*)(Ls + 8192 + r * 64 + (((s * 4 + lq) ^ (r & 7)) << 3));
        }
    };
    auto mm = [&](v8bf (&a)[2][2], v8bf (&b)[3][2], v4f (&ac)[2][3]) {
        __builtin_amdgcn_s_setprio(1);
        #pragma unroll
        for (int s = 0; s < 2; ++s)
            #pragma unroll
            for (int i = 0; i < 2; ++i)
                #pragma unroll
                for (int n = 0; n < 3; ++n)
                    ac[i][n] = MFMA16(a[i][s], b[n][s], ac[i][n]);
        __builtin_amdgcn_s_setprio(0);
    };

    const int NT = 12;  // 768/64
    // prologue: buffer0 <- tile0, order A-lo, B-lo, A-hi, B-hi
    stA(0, 0, 0); stB(0, 0, 0, 0); stB(0, 0, 1, 0); stB(0, 0, 2, 0);
    stA(0, 1, 0); stB(0, 1, 0, 0); stB(0, 1, 1, 0); stB(0, 1, 2, 0);
    asm volatile("s_waitcnt vmcnt(3)" ::: "memory");   // Alo,Blo,Ahi landed
    __builtin_amdgcn_s_barrier();
    rdA(aS1, lds[0], 0); rdB(bS4, lds[0], 0);

    for (int t = 0; t < NT; ++t) {
        const int cur = t & 1, nxt = cur ^ 1;
        const int kk2 = (t + 1 < NT ? t + 1 : t) * 64;
        const bf16* Ls = lds[cur];
        const bf16* Ln = lds[nxt];

        // ph0: MFMA m0n0 (aS1 x bS4); rd cur.Ahi->aS2; stage nxt.Alo
        rdA(aS2, Ls, 1);
        stA(nxt, 0, kk2);
        mm(aS1, bS4, acc[0][0]);
        asm volatile("s_waitcnt vmcnt(1)" ::: "memory");   // cur.Bhi landed
        __builtin_amdgcn_s_barrier();

        // ph1: MFMA m1n0 (aS2 x bS4); rd cur.Bhi->bS5; stage nxt.Blo
        rdB(bS5, Ls, 1);
        stB(nxt, 0, 0, kk2); stB(nxt, 0, 1, kk2); stB(nxt, 0, 2, kk2);
        mm(aS2, bS4, acc[1][0]);
        __builtin_amdgcn_s_barrier();

        // ph2: MFMA m1n1 (aS2 x bS5); rd cur.Alo->aS3; stage nxt.Ahi
        rdA(aS3, Ls, 0);
        stA(nxt, 1, kk2);
        mm(aS2, bS5, acc[1][1]);
        asm volatile("s_waitcnt vmcnt(1)" ::: "memory");   // nxt.Alo,Blo landed
        __builtin_amdgcn_s_barrier();

        // ph3: MFMA m0n1 (aS3 x bS5); rd nxt.Alo->aS1, nxt.Blo->bS4; stage nxt.Bhi
        rdA(aS1, Ln, 0); rdB(bS4, Ln, 0);
        stB(nxt, 1, 0, kk2); stB(nxt, 1, 1, kk2); stB(nxt, 1, 2, kk2);
        mm(aS3, bS5, acc[0][1]);
        asm volatile("s_waitcnt vmcnt(3)" ::: "memory");   // nxt.Ahi landed
        __builtin_amdgcn_s_barrier();
    }
    asm volatile("s_waitcnt vmcnt(0)" ::: "memory");

    const bool isQ = (n0 < 768);
    const float* bias = isQ ? bq : bk;
    const float sc = isQ ? qscale : 1.0f;
    bf16* C = isQ ? Qb : Kb;
    const int c0 = isQ ? n0 : n0 - 768;

    #pragma unroll
    for (int mh = 0; mh < 2; ++mh)
    #pragma unroll
    for (int i = 0; i < 2; ++i) {
        #pragma unroll
        for (int rr = 0; rr < 4; ++rr) {
            const int row = m0 + mh * 64 + wr * 32 + i * 16 + lq * 4 + rr;
            #pragma unroll
            for (int nh = 0; nh < 2; ++nh)
                #pragma unroll
                for (int n = 0; n < 3; ++n) {
                    const int col = c0 + nh * 192 + wc * 48 + n * 16 + lr;
                    C[(long)row * 768 + col] = (bf16)((acc[mh][nh][i][n][rr] + bias[col]) * sc);
                }
        }
    }
}

// ---------------------------------------------------------------------------
// Kernel 4: E = exp(Q.K^T) + row-sum atomics into L. R5 template:
// 256x256 tile, BK=64 (128-B rows, proven zero-conflict XOR swizzle), dbuf
// 2x64KB, 4 barriers/K-tile (half of R4), read-one-phase-ahead into 3 A-sets /
// 2 B-sets, uniform counted vmcnt(2) before every barrier (ledger-verified,
// 2-6 loads always in flight, never drained in-loop).
// grid 512: batch = bx&7 (XCD), j = bx>>3: mt=j>>3, nt=j&7.
// ---------------------------------------------------------------------------
__global__ __launch_bounds__(512, 2)
void gemm_scores(const bf16* __restrict__ Q, const bf16* __restrict__ K,
                 bf16* __restrict__ E, float* __restrict__ L)
{
    __shared__ __attribute__((aligned(16))) bf16 lds[2][32768];  // 2 x 64 KB

    const int bx = blockIdx.x;
    const int batch = bx & 7, j = bx >> 3;      // j in [0,64)
    const int m0 = (j >> 3) * 256, n0 = (j & 7) * 256;

    const bf16* Ag = Q + (long)batch * 2048 * 768 + (long)m0 * 768;
    const bf16* Bg = K + (long)batch * 2048 * 768 + (long)n0 * 768;
    bf16* C = E + (long)batch * 2048 * 2048;
    float* Lb = L + (long)batch * 2048;

    const int tid = threadIdx.x, wv = tid >> 6, lane = tid & 63;
    const int wr = wv >> 2, wc = wv & 3;
    const int lr = lane & 15, lq = lane >> 4;

    auto stA = [&](int bi, int h, int p, int kk) {     // 2 instr/wave, 16 KB half
        const int lin = (wv * 2 + p) * 64 + lane;      // 0..1023
        const int r = lin >> 3, ck = (lin & 7) ^ (r & 7);
        gload_lds16(Ag + (long)(h * 128 + r) * 768 + kk + ck * 8,
                    (char*)lds + bi * 65536 + h * 16384 + lin * 16);
    };
    auto stB = [&](int bi, int h, int p, int kk) {
        const int lin = (wv * 2 + p) * 64 + lane;
        const int r = lin >> 3, ck = (lin & 7) ^ (r & 7);
        gload_lds16(Bg + (long)(h * 128 + r) * 768 + kk + ck * 8,
                    (char*)lds + bi * 65536 + 32768 + h * 16384 + lin * 16);
    };

    v8bf aS1[4][2], aS2[4][2], aS3[4][2], bS4[2][2], bS5[2][2];
    v4f acc[2][2][4][2] = {};   // [mh][nh][i][n]

    auto rdA = [&](v8bf (&d)[4][2], const bf16* Ls, int mh) {
        #pragma unroll
        for (int i = 0; i < 4; ++i) {
            const int r = mh * 128 + wr * 64 + i * 16 + lr;
            #pragma unroll
            for (int s = 0; s < 2; ++s)
                d[i][s] = *(const v8bf*)(Ls + r * 64 + (((s * 4 + lq) ^ (r & 7)) << 3));
        }
    };
    auto rdB = [&](v8bf (&d)[2][2], const bf16* Ls, int nh) {
        #pragma unroll
        for (int n = 0; n < 2; ++n) {
            const int r = nh * 128 + wc * 32 + n * 16 + lr;
            #pragma unroll
            for (int s = 0; s < 2; ++s)
                d[n][s] = *(const v8bf*)(Ls + 16384 + r * 64 + (((s * 4 + lq) ^ (r & 7)) << 3));
        }
    };
    auto mm = [&](v8bf (&a)[4][2], v8bf (&b)[2][2], v4f (&ac)[4][2]) {
        __builtin_amdgcn_s_setprio(1);
        #pragma unroll
        for (int s = 0; s < 2; ++s)
            #pragma unroll
            for (int i = 0; i < 4; ++i)
                #pragma unroll
                for (int n = 0; n < 2; ++n)
                    ac[i][n] = MFMA16(a[i][s], b[n][s], ac[i][n]);
        __builtin_amdgcn_s_setprio(0);
    };

    const int NT = 12;  // 768/64
    // prologue: buffer0 <- tile0, order A-lo, B-lo, A-hi, B-hi
    stA(0, 0, 0, 0); stA(0, 0, 1, 0); stB(0, 0, 0, 0); stB(0, 0, 1, 0);
    stA(0, 1, 0, 0); stA(0, 1, 1, 0); stB(0, 1, 0, 0); stB(0, 1, 1, 0);
    asm volatile("s_waitcnt vmcnt(2)" ::: "memory");   // Alo,Blo,Ahi landed
    __builtin_amdgcn_s_barrier();
    rdA(aS1, lds[0], 0); rdB(bS4, lds[0], 0);

    for (int t = 0; t < NT; ++t) {
        const int cur = t & 1, nxt = cur ^ 1;
        const int kk2 = (t + 1 < NT ? t + 1 : t) * 64;
        const bf16* Ls = lds[cur];
        const bf16* Ln = lds[nxt];

        // ph0: MFMA m0n0 (aS1 x bS4); rd cur.Ahi->aS2; stage nxt.Alo
        rdA(aS2, Ls, 1);
        stA(nxt, 0, 0, kk2); stA(nxt, 0, 1, kk2);
        mm(aS1, bS4, acc[0][0]);
        asm volatile("s_waitcnt vmcnt(2)" ::: "memory");   // cur.Bhi landed
        __builtin_amdgcn_s_barrier();

        // ph1: MFMA m1n0 (aS2 x bS4); rd cur.Bhi->bS5; stage nxt.Blo
        rdB(bS5, Ls, 1);
        stB(nxt, 0, 0, kk2); stB(nxt, 0, 1, kk2);
        mm(aS2, bS4, acc[1][0]);
        asm volatile("s_waitcnt vmcnt(2)" ::: "memory");   // nxt.Alo landed
        __builtin_amdgcn_s_barrier();

        // ph2: MFMA m1n1 (aS2 x bS5); rd cur.Alo->aS3; stage nxt.Ahi
        rdA(aS3, Ls, 0);
        stA(nxt, 1, 0, kk2); stA(nxt, 1, 1, kk2);
        mm(aS2, bS5, acc[1][1]);
        asm volatile("s_waitcnt vmcnt(2)" ::: "memory");   // nxt.Blo landed
        __builtin_amdgcn_s_barrier();

        // ph3: MFMA m0n1 (aS3 x bS5); rd nxt.Alo->aS1, nxt.Blo->bS4; stage nxt.Bhi
        rdA(aS1, Ln, 0); rdB(bS4, Ln, 0);
        stB(nxt, 1, 0, kk2); stB(nxt, 1, 1, kk2);
        mm(aS3, bS5, acc[0][1]);
        asm volatile("s_waitcnt vmcnt(2)" ::: "memory");   // nxt.Ahi landed
        __builtin_amdgcn_s_barrier();
    }
    asm volatile("s_waitcnt vmcnt(0)" ::: "memory");

    // epilogue: exp + 16-lane row-sum reduce + atomics + bf16 store
    #pragma unroll
    for (int mh = 0; mh < 2; ++mh)
    #pragma unroll
    for (int i = 0; i < 4; ++i) {
        #pragma unroll
        for (int rr = 0; rr < 4; ++rr) {
            const int row = m0 + mh * 128 + wr * 64 + i * 16 + lq * 4 + rr;
            float e[4], rs = 0.f;
            #pragma unroll
            for (int nh = 0; nh < 2; ++nh)
                #pragma unroll
                for (int n = 0; n < 2; ++n) {
                    e[nh * 2 + n] = __expf(acc[mh][nh][i][n][rr]);
                    rs += e[nh * 2 + n];
                }
            #pragma unroll
            for (int off = 1; off < 16; off <<= 1) rs += __shfl_xor(rs, off);
            if (lr == 0) atomicAdd(&Lb[row], rs);
            #pragma unroll
            for (int nh = 0; nh < 2; ++nh)
                #pragma unroll
                for (int n = 0; n < 2; ++n) {
                    const int col = n0 + nh * 128 + wc * 32 + n * 16 + lr;
                    C[(long)row * 2048 + col] = (bf16)e[nh * 2 + n];
                }
        }
    }
}

// ---------------------------------------------------------------------------
// Kernel 5: Out = (E.V^T)/L + Xres. R5 template, 128(M)x384(N), BK=64,
// NT=32, dbuf 2x64KB, 4 barriers/K-tile, vmcnt ledger (1/-/1/3).
// grid 256 = 1 block/CU: batch = bx&7, j = bx>>3: mt=j>>1, nt=j&1.
// ---------------------------------------------------------------------------
__global__ __launch_bounds__(512, 2)
void gemm_pv(const bf16* __restrict__ P, const bf16* __restrict__ VT,
             const float* __restrict__ L, const float* __restrict__ Xres,
             float* __restrict__ Out)
{
    __shared__ __attribute__((aligned(16))) bf16 lds[2][32768];  // 2 x 64 KB

    const int bx = blockIdx.x;
    const int batch = bx & 7, j = bx >> 3;   // j in [0,32)
    const int m0 = (j >> 1) * 128;
    const int n0 = (j & 1) * 384;

    const bf16* Ag = P  + (long)batch * 2048 * 2048 + (long)m0 * 2048;
    const bf16* Bg = VT + (long)batch * 768 * 2048  + (long)n0 * 2048;
    const float* Lb = L + (long)batch * 2048;
    const float* Xr = Xres + (long)batch * 2048 * 768;
    float* O = Out + (long)batch * 2048 * 768;

    const int tid = threadIdx.x, wv = tid >> 6, lane = tid & 63;
    const int wr = wv >> 2, wc = wv & 3;
    const int lr = lane & 15, lq = lane >> 4;

    auto stA = [&](int bi, int h, int kk) {
        const int lin = wv * 64 + lane;
        const int r = lin >> 3, ck = (lin & 7) ^ (r & 7);
        gload_lds16(Ag + (long)(h * 64 + r) * 2048 + kk + ck * 8,
                    (char*)lds + bi * 65536 + h * 8192 + lin * 16);
    };
    auto stB = [&](int bi, int h, int p, int kk) {
        const int lin = (wv * 3 + p) * 64 + lane;
        const int r = lin >> 3, ck = (lin & 7) ^ (r & 7);
        gload_lds16(Bg + (long)(h * 192 + r) * 2048 + kk + ck * 8,
                    (char*)lds + bi * 65536 + 16384 + h * 24576 + lin * 16);
    };

    v8bf aS1[2][2], aS2[2][2], aS3[2][2], bS4[3][2], bS5[3][2];
    v4f acc[2][2][2][3] = {};   // [mh][nh][i][n]

    auto rdA = [&](v8bf (&d)[2][2], const bf16* Ls, int mh) {
        #pragma unroll
        for (int i = 0; i < 2; ++i) {
            const int r = mh * 64 + wr * 32 + i * 16 + lr;
            #pragma unroll
            for (int s = 0; s < 2; ++s)
                d[i][s] = *(const v8bf*)(Ls + r * 64 + (((s * 4 + lq) ^ (r & 7)) << 3));
        }
    };
    auto rdB = [&](v8bf (&d)[3][2], const bf16* Ls, int nh) {
        #pragma unroll
        for (int n = 0; n < 3; ++n) {
            const int r = nh * 192 + wc * 48 + n * 16 + lr;
            #pragma unroll
            for (int s = 0; s < 2; ++s)
                d[n][s] = *(const v8bf*)(Ls + 8192 + r * 64 + (((s * 4 + lq) ^ (r & 7)) << 3));
        }
    };
    auto mm = [&](v8bf (&a)[2][2], v8bf (&b)[3][2], v4f (&ac)[2][3]) {
        __builtin_amdgcn_s_setprio(1);
        #pragma unroll
        for (int s = 0; s < 2; ++s)
            #pragma unroll
            for (int i = 0; i < 2; ++i)
                #pragma unroll
                for (int n = 0; n < 3; ++n)
                    ac[i][n] = MFMA16(a[i][s], b[n][s], ac[i][n]);
        __builtin_amdgcn_s_setprio(0);
    };

    const int NT = 32;  // 2048/64
    stA(0, 0, 0); stB(0, 0, 0, 0); stB(0, 0, 1, 0); stB(0, 0, 2, 0);
    stA(0, 1, 0); stB(0, 1, 0, 0); stB(0, 1, 1, 0); stB(0, 1, 2, 0);
    asm volatile("s_waitcnt vmcnt(3)" ::: "memory");
    __builtin_amdgcn_s_barrier();
    rdA(aS1, lds[0], 0); rdB(bS4, lds[0], 0);

    for (int t = 0; t < NT; ++t) {
        const int cur = t & 1, nxt = cur ^ 1;
        const int kk2 = (t + 1 < NT ? t + 1 : t) * 64;
        const bf16* Ls = lds[cur];
        const bf16* Ln = lds[nxt];

        // ph0
        rdA(aS2, Ls, 1);
        stA(nxt, 0, kk2);
        mm(aS1, bS4, acc[0][0]);
        asm volatile("s_waitcnt vmcnt(1)" ::: "memory");
        __builtin_amdgcn_s_barrier();

        // ph1
        rdB(bS5, Ls, 1);
        stB(nxt, 0, 0, kk2); stB(nxt, 0, 1, kk2); stB(nxt, 0, 2, kk2);
        mm(aS2, bS4, acc[1][0]);
        __builtin_amdgcn_s_barrier();

        // ph2
        rdA(aS3, Ls, 0);
        stA(nxt, 1, kk2);
        mm(aS2, bS5, acc[1][1]);
        asm volatile("s_waitcnt vmcnt(1)" ::: "memory");
        __builtin_amdgcn_s_barrier();

        // ph3
        rdA(aS1, Ln, 0); rdB(bS4, Ln, 0);
        stB(nxt, 1, 0, kk2); stB(nxt, 1, 1, kk2); stB(nxt, 1, 2, kk2);
        mm(aS3, bS5, acc[0][1]);
        asm volatile("s_waitcnt vmcnt(3)" ::: "memory");
        __builtin_amdgcn_s_barrier();
    }
    asm volatile("s_waitcnt vmcnt(0)" ::: "memory");

    // epilogue: O = acc/L[row] + Xres
    #pragma unroll
    for (int mh = 0; mh < 2; ++mh)
    #pragma unroll
    for (int i = 0; i < 2; ++i) {
        #pragma unroll
        for (int rr = 0; rr < 4; ++rr) {
            const int row = m0 + mh * 64 + wr * 32 + i * 16 + lq * 4 + rr;
            const float invL = 1.0f / Lb[row];
            #pragma unroll
            for (int nh = 0; nh < 2; ++nh)
                #pragma unroll
                for (int n = 0; n < 3; ++n) {
                    const int col = n0 + nh * 192 + wc * 48 + n * 16 + lr;
                    const long idx = (long)row * 768 + col;
                    O[idx] = acc[mh][nh][i][n][rr] * invL + Xr[idx];
                }
        }
    }
}

// ---------------------------------------------------------------------------
extern "C" void kernel_launch(void* const* d_in, const int* in_sizes, int n_in,
                              void* d_out, int out_size, void* d_ws, size_t ws_size,
                              hipStream_t stream)
{
    const float* x    = (const float*)d_in[0];
    const float* ln_g = (const float*)d_in[1];
    const float* ln_b = (const float*)d_in[2];
    const float* Wq   = (const float*)d_in[3];
    const float* bq   = (const float*)d_in[4];
    const float* Wk   = (const float*)d_in[5];
    const float* bk   = (const float*)d_in[6];
    float* out = (float*)d_out;

    const long R = 8L * 2048;  // 16384 rows
    char* ws = (char*)d_ws;
    size_t off = 0;
    auto take = [&](size_t bytes) -> char* {
        char* p = ws + off;
        off += (bytes + 255) & ~(size_t)255;
        return p;
    };
    bf16*  xn   = (bf16*)take(R * 768 * 2);   // reused as xvT after projection
    bf16*  xv   = (bf16*)take(R * 768 * 2);
    bf16*  Qb   = (bf16*)take(R * 768 * 2);
    bf16*  Kb   = (bf16*)take(R * 768 * 2);
    bf16*  Wcat = (bf16*)take(1536L * 768 * 2);
    float* Lrow = (float*)take(R * 4);        // softmax denominators
    bf16*  Sc   = (bf16*)take(8L * 2048 * 2048 * 2);  // E = exp(scores)

    ln_cast<<<R, 256, 0, stream>>>(x, ln_g, ln_b, xn, xv, Lrow);
    cvt_w<<<dim3(576, 2), 256, 0, stream>>>(Wq, Wk, Wcat);

    const float qscale = 0.036084391824351615f;  // 1/sqrt(768), folded into Q
    gemm_qk<<<512, 512, 0, stream>>>(xn, Wcat, bq, bk, qscale, Qb, Kb);

    // xn dead now; reuse its buffer for xvT [8][768][2048]
    bf16* xvT = xn;
    transpose_bf<<<dim3(32, 12, 8), 256, 0, stream>>>(xv, xvT);

    gemm_scores<<<512, 512, 0, stream>>>(Qb, Kb, Sc, Lrow);
    gemm_pv<<<256, 512, 0, stream>>>(Sc, xvT, Lrow, x, out);
}

// Round 7
// 319.381 us; speedup vs baseline: 1.1577x; 1.1577x over previous
//
#include <hip/hip_runtime.h>

typedef __bf16 bf16;
typedef __bf16 v8bf __attribute__((ext_vector_type(8)));
typedef __bf16 v4bf __attribute__((ext_vector_type(4)));
typedef float  v4f  __attribute__((ext_vector_type(4)));

__device__ __forceinline__ void gload_lds16(const void* g, void* l) {
    __builtin_amdgcn_global_load_lds(
        (const __attribute__((address_space(1))) void*)g,
        (__attribute__((address_space(3))) void*)l, 16, 0, 0);
}

#define MFMA16(a, b, c) __builtin_amdgcn_mfma_f32_16x16x32_bf16((a), (b), (c), 0, 0, 0)

// ---------------------------------------------------------------------------
// Kernel 1: LayerNorm over D=768 + bf16 casts. One block per row, 256 thr.
// Blocks 0..63 also zero the softmax row-sum accumulator L (16384 floats).
// ---------------------------------------------------------------------------
__global__ __launch_bounds__(256)
void ln_cast(const float* __restrict__ x, const float* __restrict__ g,
             const float* __restrict__ b, bf16* __restrict__ xn,
             bf16* __restrict__ xv, float* __restrict__ L)
{
    const long row = blockIdx.x;
    const float* xr = x + row * 768;
    const int tid = threadIdx.x;
    const int wave = tid >> 6, lane = tid & 63;

    if (row < 64) L[row * 256 + tid] = 0.0f;

    float a0 = xr[tid], a1 = xr[tid + 256], a2 = xr[tid + 512];
    float s = a0 + a1 + a2;
    #pragma unroll
    for (int off = 32; off; off >>= 1) s += __shfl_xor(s, off);
    __shared__ float sh[4], sh2[4];
    if (!lane) sh[wave] = s;
    __syncthreads();
    const float mu = (sh[0] + sh[1] + sh[2] + sh[3]) * (1.0f / 768.0f);

    float d0 = a0 - mu, d1 = a1 - mu, d2 = a2 - mu;
    float ss = d0 * d0 + d1 * d1 + d2 * d2;
    #pragma unroll
    for (int off = 32; off; off >>= 1) ss += __shfl_xor(ss, off);
    if (!lane) sh2[wave] = ss;
    __syncthreads();
    const float var = (sh2[0] + sh2[1] + sh2[2] + sh2[3]) * (1.0f / 768.0f);
    const float rstd = rsqrtf(var + 1e-5f);

    bf16* xnr = xn + row * 768;
    bf16* xvr = xv + row * 768;
    xnr[tid]       = (bf16)(d0 * rstd * g[tid]       + b[tid]);
    xnr[tid + 256] = (bf16)(d1 * rstd * g[tid + 256] + b[tid + 256]);
    xnr[tid + 512] = (bf16)(d2 * rstd * g[tid + 512] + b[tid + 512]);
    xvr[tid]       = (bf16)a0;
    xvr[tid + 256] = (bf16)a1;
    xvr[tid + 512] = (bf16)a2;
}

// ---------------------------------------------------------------------------
// Kernel 2: weight fp32 -> bf16 convert into Wcat halves. grid (576,2).
// ---------------------------------------------------------------------------
__global__ __launch_bounds__(256)
void cvt_w(const float* __restrict__ Wq, const float* __restrict__ Wk,
           bf16* __restrict__ Wcat)
{
    const int z = blockIdx.y;
    const float* src = z ? Wk : Wq;
    bf16* dst = Wcat + (long)z * 768 * 768;
    const int i = (blockIdx.x * 256 + threadIdx.x) * 4;
    const float4 v = *(const float4*)(src + i);
    v4bf o = {(bf16)v.x, (bf16)v.y, (bf16)v.z, (bf16)v.w};
    *(v4bf*)(dst + i) = o;
}

// ---------------------------------------------------------------------------
// Kernel 2b: 64x64-tile bf16 transpose, XOR-swizzled LDS (conflict-free).
// in: [B][2048][768] -> outT: [B][768][2048]. grid (32, 12, 8), 256 thr.
// ---------------------------------------------------------------------------
__global__ __launch_bounds__(256)
void transpose_bf(const bf16* __restrict__ in, bf16* __restrict__ outT)
{
    __shared__ __attribute__((aligned(16))) bf16 tile[64 * 64];
    const int t0 = blockIdx.x * 64, d0 = blockIdx.y * 64;
    in   += (long)blockIdx.z * 2048 * 768;
    outT += (long)blockIdx.z * 768 * 2048;
    const int tid = threadIdx.x;

    #pragma unroll
    for (int it = 0; it < 2; ++it) {
        const int lin = it * 256 + tid;
        const int r = lin >> 3;
        const int g = lin & 7;
        const int pg = g ^ (r & 7) ^ ((r >> 3) & 7);
        v8bf v = *(const v8bf*)(in + (long)(t0 + r) * 768 + d0 + g * 8);
        *(v8bf*)(tile + r * 64 + pg * 8) = v;
    }
    __syncthreads();
    #pragma unroll
    for (int it = 0; it < 2; ++it) {
        const int lin = it * 256 + tid;
        const int dd = lin >> 3;
        const int tb = lin & 7;
        v8bf o;
        #pragma unroll
        for (int j = 0; j < 8; ++j) {
            const int t = tb * 8 + j;
            const int pg = (dd >> 3) ^ (t & 7) ^ ((t >> 3) & 7);
            o[j] = tile[t * 64 + pg * 8 + (dd & 7)];
        }
        *(v8bf*)(outT + (long)(d0 + dd) * 2048 + t0 + tb * 8) = o;
    }
}

// ---------------------------------------------------------------------------
// Kernel 3: merged Q/K projection, R5 template. A=xn [16384,768],
// W=Wcat [1536,768]. 128(M)x384(N) tile, BK=64, dbuf 2x64KB, 4 barriers per
// K-tile, read-one-phase-ahead, counted vmcnt ledger (1/-/1/3).
// grid 512 = 2 full rounds. XCD chunking: wg=(bx&7)*64+(bx>>3).
// ---------------------------------------------------------------------------
__global__ __launch_bounds__(512, 2)
void gemm_qk(const bf16* __restrict__ A, const bf16* __restrict__ W,
             const float* __restrict__ bq, const float* __restrict__ bk,
             float qscale, bf16* __restrict__ Qb, bf16* __restrict__ Kb)
{
    __shared__ __attribute__((aligned(16))) bf16 lds[2][32768];  // 2 x 64 KB

    const int bx = blockIdx.x;
    const int wg = (bx & 7) * 64 + (bx >> 3);   // XCD-contiguous
    const int m0 = (wg >> 2) * 128;             // 0..16256
    const int n0 = (wg & 3) * 384;              // 0,384,768,1152

    const bf16* Ag = A + (long)m0 * 768;
    const bf16* Bg = W + (long)n0 * 768;

    const int tid = threadIdx.x, wv = tid >> 6, lane = tid & 63;
    const int wr = wv >> 2, wc = wv & 3;
    const int lr = lane & 15, lq = lane >> 4;

    auto stA = [&](int bi, int h, int kk) {            // 1 instr/wave, 8 KB half
        const int lin = wv * 64 + lane;                // 0..511
        const int r = lin >> 3, ck = (lin & 7) ^ (r & 7);
        gload_lds16(Ag + (long)(h * 64 + r) * 768 + kk + ck * 8,
                    (char*)lds + bi * 65536 + h * 8192 + lin * 16);
    };
    auto stB = [&](int bi, int h, int p, int kk) {     // 3 instr/wave, 24 KB half
        const int lin = (wv * 3 + p) * 64 + lane;      // 0..1535
        const int r = lin >> 3, ck = (lin & 7) ^ (r & 7);
        gload_lds16(Bg + (long)(h * 192 + r) * 768 + kk + ck * 8,
                    (char*)lds + bi * 65536 + 16384 + h * 24576 + lin * 16);
    };

    v8bf aS1[2][2], aS2[2][2], aS3[2][2], bS4[3][2], bS5[3][2];
    v4f acc[2][2][2][3] = {};   // [mh][nh][i][n]

    auto rdA = [&](v8bf (&d)[2][2], const bf16* Ls, int mh) {
        #pragma unroll
        for (int i = 0; i < 2; ++i) {
            const int r = mh * 64 + wr * 32 + i * 16 + lr;
            #pragma unroll
            for (int s = 0; s < 2; ++s)
                d[i][s] = *(const v8bf*)(Ls + r * 64 + (((s * 4 + lq) ^ (r & 7)) << 3));
        }
    };
    auto rdB = [&](v8bf (&d)[3][2], const bf16* Ls, int nh) {
        #pragma unroll
        for (int n = 0; n < 3; ++n) {
            const int r = nh * 192 + wc * 48 + n * 16 + lr;
            #pragma unroll
            for (int s = 0; s < 2; ++s)
                d[n][s] = *(const v8bf*)(Ls + 8192 + r * 64 + (((s * 4 + lq) ^ (r & 7)) << 3));
        }
    };
    auto mm = [&](v8bf (&a)[2][2], v8bf (&b)[3][2], v4f (&ac)[2][3]) {
        __builtin_amdgcn_s_setprio(1);
        #pragma unroll
        for (int s = 0; s < 2; ++s)
            #pragma unroll
            for (int i = 0; i < 2; ++i)
                #pragma unroll
                for (int n = 0; n < 3; ++n)
                    ac[i][n] = MFMA16(a[i][s], b[n][s], ac[i][n]);
        __builtin_amdgcn_s_setprio(0);
    };

    const int NT = 12;  // 768/64
    // prologue: buffer0 <- tile0, order A-lo, B-lo, A-hi, B-hi
    stA(0, 0, 0); stB(0, 0, 0, 0); stB(0, 0, 1, 0); stB(0, 0, 2, 0);
    stA(0, 1, 0); stB(0, 1, 0, 0); stB(0, 1, 1, 0); stB(0, 1, 2, 0);
    asm volatile("s_waitcnt vmcnt(3)" ::: "memory");   // Alo,Blo,Ahi landed
    __builtin_amdgcn_s_barrier();
    rdA(aS1, lds[0], 0); rdB(bS4, lds[0], 0);

    for (int t = 0; t < NT; ++t) {
        const int cur = t & 1, nxt = cur ^ 1;
        const int kk2 = (t + 1 < NT ? t + 1 : t) * 64;
        const bf16* Ls = lds[cur];
        const bf16* Ln = lds[nxt];

        // ph0: MFMA m0n0 (aS1 x bS4); rd cur.Ahi->aS2; stage nxt.Alo
        rdA(aS2, Ls, 1);
        stA(nxt, 0, kk2);
        mm(aS1, bS4, acc[0][0]);
        asm volatile("s_waitcnt vmcnt(1)" ::: "memory");   // cur.Bhi landed
        __builtin_amdgcn_s_barrier();

        // ph1: MFMA m1n0 (aS2 x bS4); rd cur.Bhi->bS5; stage nxt.Blo
        rdB(bS5, Ls, 1);
        stB(nxt, 0, 0, kk2); stB(nxt, 0, 1, kk2); stB(nxt, 0, 2, kk2);
        mm(aS2, bS4, acc[1][0]);
        __builtin_amdgcn_s_barrier();

        // ph2: MFMA m1n1 (aS2 x bS5); rd cur.Alo->aS3; stage nxt.Ahi
        rdA(aS3, Ls, 0);
        stA(nxt, 1, kk2);
        mm(aS2, bS5, acc[1][1]);
        asm volatile("s_waitcnt vmcnt(1)" ::: "memory");   // nxt.Alo,Blo landed
        __builtin_amdgcn_s_barrier();

        // ph3: MFMA m0n1 (aS3 x bS5); rd nxt.Alo->aS1, nxt.Blo->bS4; stage nxt.Bhi
        rdA(aS1, Ln, 0); rdB(bS4, Ln, 0);
        stB(nxt, 1, 0, kk2); stB(nxt, 1, 1, kk2); stB(nxt, 1, 2, kk2);
        mm(aS3, bS5, acc[0][1]);
        asm volatile("s_waitcnt vmcnt(3)" ::: "memory");   // nxt.Ahi landed
        __builtin_amdgcn_s_barrier();
    }
    asm volatile("s_waitcnt vmcnt(0)" ::: "memory");

    const bool isQ = (n0 < 768);
    const float* bias = isQ ? bq : bk;
    const float sc = isQ ? qscale : 1.0f;
    bf16* C = isQ ? Qb : Kb;
    const int c0 = isQ ? n0 : n0 - 768;

    #pragma unroll
    for (int mh = 0; mh < 2; ++mh)
    #pragma unroll
    for (int i = 0; i < 2; ++i) {
        #pragma unroll
        for (int rr = 0; rr < 4; ++rr) {
            const int row = m0 + mh * 64 + wr * 32 + i * 16 + lq * 4 + rr;
            #pragma unroll
            for (int nh = 0; nh < 2; ++nh)
                #pragma unroll
                for (int n = 0; n < 3; ++n) {
                    const int col = c0 + nh * 192 + wc * 48 + n * 16 + lr;
                    C[(long)row * 768 + col] = (bf16)((acc[mh][nh][i][n][rr] + bias[col]) * sc);
                }
        }
    }
}

// ---------------------------------------------------------------------------
// Kernel 4: E = exp(Q.K^T) + row-sum atomics into L.  R6: spill-free
// read-ahead. 128(M)x256(N) tile, 8 waves (wave 64x64, acc=64 AGPR),
// BK=64 zero-conflict XOR layout, dbuf 2x48KB, 4 gray phases/K-tile
// (m0n0, m1n0, m1n1, m0n1), EXACTLY 4 frag sets (A0,A1,B0,B1 = 64 VGPR)
// via 2-iteration unroll with A0/A1 role swap. Per-wave ledger:
// waits vmcnt(1)/-/vmcnt(1)/vmcnt(2); 1-4 loads in flight, never drained.
// grid 1024: batch = bx&7 (XCD), j = bx>>3: mt=j>>3 (16), nt=j&7 (8).
// ---------------------------------------------------------------------------
__global__ __launch_bounds__(512, 2)
void gemm_scores(const bf16* __restrict__ Q, const bf16* __restrict__ K,
                 bf16* __restrict__ E, float* __restrict__ L)
{
    __shared__ __attribute__((aligned(16))) bf16 lds[2][24576];  // 2 x 48 KB

    const int bx = blockIdx.x;
    const int batch = bx & 7, j = bx >> 3;      // j in [0,128)
    const int m0 = (j >> 3) * 128, n0 = (j & 7) * 256;

    const bf16* Ag = Q + (long)batch * 2048 * 768 + (long)m0 * 768;
    const bf16* Bg = K + (long)batch * 2048 * 768 + (long)n0 * 768;
    bf16* C = E + (long)batch * 2048 * 2048;
    float* Lb = L + (long)batch * 2048;

    const int tid = threadIdx.x, wv = tid >> 6, lane = tid & 63;
    const int wr = wv >> 2, wc = wv & 3;        // waves: 2(M) x 4(N)
    const int lr = lane & 15, lq = lane >> 4;

    auto stA = [&](int bi, int h, int kk) {      // 1 load/wave, 8 KB half
        const int lin = wv * 64 + lane;          // 0..511
        const int r = lin >> 3, ck = (lin & 7) ^ (r & 7);
        gload_lds16(Ag + (long)(h * 64 + r) * 768 + kk + ck * 8,
                    (char*)lds + bi * 49152 + h * 8192 + lin * 16);
    };
    auto stB = [&](int bi, int h, int p, int kk) {  // 2 loads/wave, 16 KB half
        const int lin = (wv * 2 + p) * 64 + lane;   // 0..1023
        const int r = lin >> 3, ck = (lin & 7) ^ (r & 7);
        gload_lds16(Bg + (long)(h * 128 + r) * 768 + kk + ck * 8,
                    (char*)lds + bi * 49152 + 16384 + h * 16384 + lin * 16);
    };

    v8bf A0[2][2], A1[2][2], B0[2][2], B1[2][2];
    v4f acc[2][2][2][2] = {};   // [mh][nh][i][n]

    auto rdA = [&](v8bf (&d)[2][2], const bf16* Ls, int mh) {
        #pragma unroll
        for (int i = 0; i < 2; ++i) {
            const int r = wr * 32 + i * 16 + lr;      // within-half row
            #pragma unroll
            for (int s = 0; s < 2; ++s)
                d[i][s] = *(const v8bf*)(Ls + mh * 4096 + r * 64 +
                                         (((s * 4 + lq) ^ (r & 7)) << 3));
        }
    };
    auto rdB = [&](v8bf (&d)[2][2], const bf16* Ls, int nh) {
        #pragma unroll
        for (int n = 0; n < 2; ++n) {
            const int c = wc * 32 + n * 16 + lr;      // within-half col
            #pragma unroll
            for (int s = 0; s < 2; ++s)
                d[n][s] = *(const v8bf*)(Ls + 8192 + nh * 8192 + c * 64 +
                                         (((s * 4 + lq) ^ (c & 7)) << 3));
        }
    };
    auto mm = [&](v8bf (&a)[2][2], v8bf (&b)[2][2], v4f (&ac)[2][2]) {
        __builtin_amdgcn_s_setprio(1);
        #pragma unroll
        for (int s = 0; s < 2; ++s)
            #pragma unroll
            for (int i = 0; i < 2; ++i)
                #pragma unroll
                for (int n = 0; n < 2; ++n)
                    ac[i][n] = MFMA16(a[i][s], b[n][s], ac[i][n]);
        __builtin_amdgcn_s_setprio(0);
    };

    const int NT = 12;  // 768/64
    // prologue: buffer0 <- tile0, order Alo, Blo(x2), Ahi, Bhi(x2)
    stA(0, 0, 0); stB(0, 0, 0, 0); stB(0, 0, 1, 0);
    stA(0, 1, 0); stB(0, 1, 0, 0); stB(0, 1, 1, 0);
    asm volatile("s_waitcnt vmcnt(2)" ::: "memory");  // Alo,Blo,Ahi landed
    __builtin_amdgcn_s_barrier();
    rdA(A0, lds[0], 0); rdB(B0, lds[0], 0);

    #pragma unroll 1
    for (int t = 0; t < NT; t += 2) {
        const int kk1 = (t + 1) * 64;                       // <= 11*64
        const int kk2 = (t + 2 < NT ? t + 2 : NT - 1) * 64; // clamped tail
        const bf16* Lc = lds[0];
        const bf16* Ln = lds[1];

        // ===== even iter: cur=lds[0], stage->lds[1]; A-lo in A0 =====
        // ph0 (m0n0): mm(A0,B0); rd A1<-cur.Ahi; st nxt.Alo
        rdA(A1, Lc, 1);
        stA(1, 0, kk1);
        mm(A0, B0, acc[0][0]);
        asm volatile("s_waitcnt vmcnt(1)" ::: "memory");   // cur.Bhi landed
        __builtin_amdgcn_s_barrier();

        // ph1 (m1n0): mm(A1,B0); rd B1<-cur.Bhi; st nxt.Blo
        rdB(B1, Lc, 1);
        stB(1, 0, 0, kk1); stB(1, 0, 1, kk1);
        mm(A1, B0, acc[1][0]);
        __builtin_amdgcn_s_barrier();

        // ph2 (m1n1): mm(A1,B1); st nxt.Ahi
        stA(1, 1, kk1);
        mm(A1, B1, acc[1][1]);
        asm volatile("s_waitcnt vmcnt(1)" ::: "memory");   // nxt.Alo,Blo landed
        __builtin_amdgcn_s_barrier();

        // ph3 (m0n1): mm(A0,B1); rd A1<-nxt.Alo, B0<-nxt.Blo; st nxt.Bhi
        rdA(A1, Ln, 0); rdB(B0, Ln, 0);
        stB(1, 1, 0, kk1); stB(1, 1, 1, kk1);
        mm(A0, B1, acc[0][1]);
        asm volatile("s_waitcnt vmcnt(2)" ::: "memory");   // nxt.Ahi landed
        __builtin_amdgcn_s_barrier();

        // ===== odd iter: cur=lds[1], stage->lds[0]; A-lo in A1 =====
        // ph0 (m0n0): mm(A1,B0); rd A0<-cur.Ahi; st nxt.Alo
        rdA(A0, Ln, 1);
        stA(0, 0, kk2);
        mm(A1, B0, acc[0][0]);
        asm volatile("s_waitcnt vmcnt(1)" ::: "memory");   // cur.Bhi landed
        __builtin_amdgcn_s_barrier();

        // ph1 (m1n0): mm(A0,B0); rd B1<-cur.Bhi; st nxt.Blo
        rdB(B1, Ln, 1);
        stB(0, 0, 0, kk2); stB(0, 0, 1, kk2);
        mm(A0, B0, acc[1][0]);
        __builtin_amdgcn_s_barrier();

        // ph2 (m1n1): mm(A0,B1); st nxt.Ahi
        stA(0, 1, kk2);
        mm(A0, B1, acc[1][1]);
        asm volatile("s_waitcnt vmcnt(1)" ::: "memory");   // nxt.Alo,Blo landed
        __builtin_amdgcn_s_barrier();

        // ph3 (m0n1): mm(A1,B1); rd A0<-nxt.Alo, B0<-nxt.Blo; st nxt.Bhi
        rdA(A0, Lc, 0); rdB(B0, Lc, 0);
        stB(0, 1, 0, kk2); stB(0, 1, 1, kk2);
        mm(A1, B1, acc[0][1]);
        asm volatile("s_waitcnt vmcnt(2)" ::: "memory");   // nxt.Ahi landed
        __builtin_amdgcn_s_barrier();
    }
    asm volatile("s_waitcnt vmcnt(0)" ::: "memory");

    // epilogue: exp + 16-lane row-sum reduce + atomics + bf16 store
    #pragma unroll
    for (int mh = 0; mh < 2; ++mh)
    #pragma unroll
    for (int i = 0; i < 2; ++i) {
        #pragma unroll
        for (int rr = 0; rr < 4; ++rr) {
            const int row = m0 + mh * 64 + wr * 32 + i * 16 + lq * 4 + rr;
            float e[4], rs = 0.f;
            #pragma unroll
            for (int nh = 0; nh < 2; ++nh)
                #pragma unroll
                for (int n = 0; n < 2; ++n) {
                    e[nh * 2 + n] = __expf(acc[mh][nh][i][n][rr]);
                    rs += e[nh * 2 + n];
                }
            #pragma unroll
            for (int off = 1; off < 16; off <<= 1) rs += __shfl_xor(rs, off);
            if (lr == 0) atomicAdd(&Lb[row], rs);
            #pragma unroll
            for (int nh = 0; nh < 2; ++nh)
                #pragma unroll
                for (int n = 0; n < 2; ++n) {
                    const int col = n0 + nh * 128 + wc * 32 + n * 16 + lr;
                    C[(long)row * 2048 + col] = (bf16)e[nh * 2 + n];
                }
        }
    }
}

// ---------------------------------------------------------------------------
// Kernel 5: Out = (E.V^T)/L + Xres. R5 template, 128(M)x384(N), BK=64,
// NT=32, dbuf 2x64KB, 4 barriers/K-tile, vmcnt ledger (1/-/1/3).
// grid 256 = 1 block/CU: batch = bx&7, j = bx>>3: mt=j>>1, nt=j&1.
// ---------------------------------------------------------------------------
__global__ __launch_bounds__(512, 2)
void gemm_pv(const bf16* __restrict__ P, const bf16* __restrict__ VT,
             const float* __restrict__ L, const float* __restrict__ Xres,
             float* __restrict__ Out)
{
    __shared__ __attribute__((aligned(16))) bf16 lds[2][32768];  // 2 x 64 KB

    const int bx = blockIdx.x;
    const int batch = bx & 7, j = bx >> 3;   // j in [0,32)
    const int m0 = (j >> 1) * 128;
    const int n0 = (j & 1) * 384;

    const bf16* Ag = P  + (long)batch * 2048 * 2048 + (long)m0 * 2048;
    const bf16* Bg = VT + (long)batch * 768 * 2048  + (long)n0 * 2048;
    const float* Lb = L + (long)batch * 2048;
    const float* Xr = Xres + (long)batch * 2048 * 768;
    float* O = Out + (long)batch * 2048 * 768;

    const int tid = threadIdx.x, wv = tid >> 6, lane = tid & 63;
    const int wr = wv >> 2, wc = wv & 3;
    const int lr = lane & 15, lq = lane >> 4;

    auto stA = [&](int bi, int h, int kk) {
        const int lin = wv * 64 + lane;
        const int r = lin >> 3, ck = (lin & 7) ^ (r & 7);
        gload_lds16(Ag + (long)(h * 64 + r) * 2048 + kk + ck * 8,
                    (char*)lds + bi * 65536 + h * 8192 + lin * 16);
    };
    auto stB = [&](int bi, int h, int p, int kk) {
        const int lin = (wv * 3 + p) * 64 + lane;
        const int r = lin >> 3, ck = (lin & 7) ^ (r & 7);
        gload_lds16(Bg + (long)(h * 192 + r) * 2048 + kk + ck * 8,
                    (char*)lds + bi * 65536 + 16384 + h * 24576 + lin * 16);
    };

    v8bf aS1[2][2], aS2[2][2], aS3[2][2], bS4[3][2], bS5[3][2];
    v4f acc[2][2][2][3] = {};   // [mh][nh][i][n]

    auto rdA = [&](v8bf (&d)[2][2], const bf16* Ls, int mh) {
        #pragma unroll
        for (int i = 0; i < 2; ++i) {
            const int r = mh * 64 + wr * 32 + i * 16 + lr;
            #pragma unroll
            for (int s = 0; s < 2; ++s)
                d[i][s] = *(const v8bf*)(Ls + r * 64 + (((s * 4 + lq) ^ (r & 7)) << 3));
        }
    };
    auto rdB = [&](v8bf (&d)[3][2], const bf16* Ls, int nh) {
        #pragma unroll
        for (int n = 0; n < 3; ++n) {
            const int r = nh * 192 + wc * 48 + n * 16 + lr;
            #pragma unroll
            for (int s = 0; s < 2; ++s)
                d[n][s] = *(const v8bf*)(Ls + 8192 + r * 64 + (((s * 4 + lq) ^ (r & 7)) << 3));
        }
    };
    auto mm = [&](v8bf (&a)[2][2], v8bf (&b)[3][2], v4f (&ac)[2][3]) {
        __builtin_amdgcn_s_setprio(1);
        #pragma unroll
        for (int s = 0; s < 2; ++s)
            #pragma unroll
            for (int i = 0; i < 2; ++i)
                #pragma unroll
                for (int n = 0; n < 3; ++n)
                    ac[i][n] = MFMA16(a[i][s], b[n][s], ac[i][n]);
        __builtin_amdgcn_s_setprio(0);
    };

    const int NT = 32;  // 2048/64
    stA(0, 0, 0); stB(0, 0, 0, 0); stB(0, 0, 1, 0); stB(0, 0, 2, 0);
    stA(0, 1, 0); stB(0, 1, 0, 0); stB(0, 1, 1, 0); stB(0, 1, 2, 0);
    asm volatile("s_waitcnt vmcnt(3)" ::: "memory");
    __builtin_amdgcn_s_barrier();
    rdA(aS1, lds[0], 0); rdB(bS4, lds[0], 0);

    for (int t = 0; t < NT; ++t) {
        const int cur = t & 1, nxt = cur ^ 1;
        const int kk2 = (t + 1 < NT ? t + 1 : t) * 64;
        const bf16* Ls = lds[cur];
        const bf16* Ln = lds[nxt];

        // ph0
        rdA(aS2, Ls, 1);
        stA(nxt, 0, kk2);
        mm(aS1, bS4, acc[0][0]);
        asm volatile("s_waitcnt vmcnt(1)" ::: "memory");
        __builtin_amdgcn_s_barrier();

        // ph1
        rdB(bS5, Ls, 1);
        stB(nxt, 0, 0, kk2); stB(nxt, 0, 1, kk2); stB(nxt, 0, 2, kk2);
        mm(aS2, bS4, acc[1][0]);
        __builtin_amdgcn_s_barrier();

        // ph2
        rdA(aS3, Ls, 0);
        stA(nxt, 1, kk2);
        mm(aS2, bS5, acc[1][1]);
        asm volatile("s_waitcnt vmcnt(1)" ::: "memory");
        __builtin_amdgcn_s_barrier();

        // ph3
        rdA(aS1, Ln, 0); rdB(bS4, Ln, 0);
        stB(nxt, 1, 0, kk2); stB(nxt, 1, 1, kk2); stB(nxt, 1, 2, kk2);
        mm(aS3, bS5, acc[0][1]);
        asm volatile("s_waitcnt vmcnt(3)" ::: "memory");
        __builtin_amdgcn_s_barrier();
    }
    asm volatile("s_waitcnt vmcnt(0)" ::: "memory");

    // epilogue: O = acc/L[row] + Xres
    #pragma unroll
    for (int mh = 0; mh < 2; ++mh)
    #pragma unroll
    for (int i = 0; i < 2; ++i) {
        #pragma unroll
        for (int rr = 0; rr < 4; ++rr) {
            const int row = m0 + mh * 64 + wr * 32 + i * 16 + lq * 4 + rr;
            const float invL = 1.0f / Lb[row];
            #pragma unroll
            for (int nh = 0; nh < 2; ++nh)
                #pragma unroll
                for (int n = 0; n < 3; ++n) {
                    const int col = n0 + nh * 192 + wc * 48 + n * 16 + lr;
                    const long idx = (long)row * 768 + col;
                    O[idx] = acc[mh][nh][i][n][rr] * invL + Xr[idx];
                }
        }
    }
}

// ---------------------------------------------------------------------------
extern "C" void kernel_launch(void* const* d_in, const int* in_sizes, int n_in,
                              void* d_out, int out_size, void* d_ws, size_t ws_size,
                              hipStream_t stream)
{
    const float* x    = (const float*)d_in[0];
    const float* ln_g = (const float*)d_in[1];
    const float* ln_b = (const float*)d_in[2];
    const float* Wq   = (const float*)d_in[3];
    const float* bq   = (const float*)d_in[4];
    const float* Wk   = (const float*)d_in[5];
    const float* bk   = (const float*)d_in[6];
    float* out = (float*)d_out;

    const long R = 8L * 2048;  // 16384 rows
    char* ws = (char*)d_ws;
    size_t off = 0;
    auto take = [&](size_t bytes) -> char* {
        char* p = ws + off;
        off += (bytes + 255) & ~(size_t)255;
        return p;
    };
    bf16*  xn   = (bf16*)take(R * 768 * 2);   // reused as xvT after projection
    bf16*  xv   = (bf16*)take(R * 768 * 2);
    bf16*  Qb   = (bf16*)take(R * 768 * 2);
    bf16*  Kb   = (bf16*)take(R * 768 * 2);
    bf16*  Wcat = (bf16*)take(1536L * 768 * 2);
    float* Lrow = (float*)take(R * 4);        // softmax denominators
    bf16*  Sc   = (bf16*)take(8L * 2048 * 2048 * 2);  // E = exp(scores)

    ln_cast<<<R, 256, 0, stream>>>(x, ln_g, ln_b, xn, xv, Lrow);
    cvt_w<<<dim3(576, 2), 256, 0, stream>>>(Wq, Wk, Wcat);

    const float qscale = 0.036084391824351615f;  // 1/sqrt(768), folded into Q
    gemm_qk<<<512, 512, 0, stream>>>(xn, Wcat, bq, bk, qscale, Qb, Kb);

    // xn dead now; reuse its buffer for xvT [8][768][2048]
    bf16* xvT = xn;
    transpose_bf<<<dim3(32, 12, 8), 256, 0, stream>>>(xv, xvT);

    gemm_scores<<<1024, 512, 0, stream>>>(Qb, Kb, Sc, Lrow);
    gemm_pv<<<256, 512, 0, stream>>>(Sc, xvT, Lrow, x, out);
}

// Round 9
// 307.500 us; speedup vs baseline: 1.2024x; 1.0386x over previous
//
#include <hip/hip_runtime.h>

typedef __bf16 bf16;
typedef __bf16 v8bf __attribute__((ext_vector_type(8)));
typedef __bf16 v4bf __attribute__((ext_vector_type(4)));
typedef float  v4f  __attribute__((ext_vector_type(4)));

__device__ __forceinline__ void gload_lds16(const void* g, void* l) {
    __builtin_amdgcn_global_load_lds(
        (const __attribute__((address_space(1))) void*)g,
        (__attribute__((address_space(3))) void*)l, 16, 0, 0);
}

#define MFMA16(a, b, c) __builtin_amdgcn_mfma_f32_16x16x32_bf16((a), (b), (c), 0, 0, 0)

// ---------------------------------------------------------------------------
// Kernel 1: LayerNorm over D=768 + bf16 casts. One block per row, 256 thr.
// Blocks 0..63 also zero the softmax row-sum accumulator L (16384 floats).
// ---------------------------------------------------------------------------
__global__ __launch_bounds__(256)
void ln_cast(const float* __restrict__ x, const float* __restrict__ g,
             const float* __restrict__ b, bf16* __restrict__ xn,
             bf16* __restrict__ xv, float* __restrict__ L)
{
    const long row = blockIdx.x;
    const float* xr = x + row * 768;
    const int tid = threadIdx.x;
    const int wave = tid >> 6, lane = tid & 63;

    if (row < 64) L[row * 256 + tid] = 0.0f;

    float a0 = xr[tid], a1 = xr[tid + 256], a2 = xr[tid + 512];
    float s = a0 + a1 + a2;
    #pragma unroll
    for (int off = 32; off; off >>= 1) s += __shfl_xor(s, off);
    __shared__ float sh[4], sh2[4];
    if (!lane) sh[wave] = s;
    __syncthreads();
    const float mu = (sh[0] + sh[1] + sh[2] + sh[3]) * (1.0f / 768.0f);

    float d0 = a0 - mu, d1 = a1 - mu, d2 = a2 - mu;
    float ss = d0 * d0 + d1 * d1 + d2 * d2;
    #pragma unroll
    for (int off = 32; off; off >>= 1) ss += __shfl_xor(ss, off);
    if (!lane) sh2[wave] = ss;
    __syncthreads();
    const float var = (sh2[0] + sh2[1] + sh2[2] + sh2[3]) * (1.0f / 768.0f);
    const float rstd = rsqrtf(var + 1e-5f);

    bf16* xnr = xn + row * 768;
    bf16* xvr = xv + row * 768;
    xnr[tid]       = (bf16)(d0 * rstd * g[tid]       + b[tid]);
    xnr[tid + 256] = (bf16)(d1 * rstd * g[tid + 256] + b[tid + 256]);
    xnr[tid + 512] = (bf16)(d2 * rstd * g[tid + 512] + b[tid + 512]);
    xvr[tid]       = (bf16)a0;
    xvr[tid + 256] = (bf16)a1;
    xvr[tid + 512] = (bf16)a2;
}

// ---------------------------------------------------------------------------
// Kernel 2: weight fp32 -> bf16 convert into Wcat halves. grid (576,2).
// ---------------------------------------------------------------------------
__global__ __launch_bounds__(256)
void cvt_w(const float* __restrict__ Wq, const float* __restrict__ Wk,
           bf16* __restrict__ Wcat)
{
    const int z = blockIdx.y;
    const float* src = z ? Wk : Wq;
    bf16* dst = Wcat + (long)z * 768 * 768;
    const int i = (blockIdx.x * 256 + threadIdx.x) * 4;
    const float4 v = *(const float4*)(src + i);
    v4bf o = {(bf16)v.x, (bf16)v.y, (bf16)v.z, (bf16)v.w};
    *(v4bf*)(dst + i) = o;
}

// ---------------------------------------------------------------------------
// Kernel 2b: 64x64-tile bf16 transpose, XOR-swizzled LDS (conflict-free).
// in: [B][2048][768] -> outT: [B][768][2048]. grid (32, 12, 8), 256 thr.
// ---------------------------------------------------------------------------
__global__ __launch_bounds__(256)
void transpose_bf(const bf16* __restrict__ in, bf16* __restrict__ outT)
{
    __shared__ __attribute__((aligned(16))) bf16 tile[64 * 64];
    const int t0 = blockIdx.x * 64, d0 = blockIdx.y * 64;
    in   += (long)blockIdx.z * 2048 * 768;
    outT += (long)blockIdx.z * 768 * 2048;
    const int tid = threadIdx.x;

    #pragma unroll
    for (int it = 0; it < 2; ++it) {
        const int lin = it * 256 + tid;
        const int r = lin >> 3;
        const int g = lin & 7;
        const int pg = g ^ (r & 7) ^ ((r >> 3) & 7);
        v8bf v = *(const v8bf*)(in + (long)(t0 + r) * 768 + d0 + g * 8);
        *(v8bf*)(tile + r * 64 + pg * 8) = v;
    }
    __syncthreads();
    #pragma unroll
    for (int it = 0; it < 2; ++it) {
        const int lin = it * 256 + tid;
        const int dd = lin >> 3;
        const int tb = lin & 7;
        v8bf o;
        #pragma unroll
        for (int j = 0; j < 8; ++j) {
            const int t = tb * 8 + j;
            const int pg = (dd >> 3) ^ (t & 7) ^ ((t >> 3) & 7);
            o[j] = tile[t * 64 + pg * 8 + (dd & 7)];
        }
        *(v8bf*)(outT + (long)(d0 + dd) * 2048 + t0 + tb * 8) = o;
    }
}

// ---------------------------------------------------------------------------
// Kernel 3: merged Q/K projection on the R3/pv template. A=xn [16384,768],
// W=Wcat [1536,768]. 128(M)x384(N) tile, 8 waves (wave 64x96), H-unit =
// A[128][32] 8KB + B[384][32] 24KB, ring-4 = 128KB LDS. 4 phases/K-tile,
// 1 barrier/phase, read-ahead-one-phase, vmcnt(4)/vmcnt(2) counted waits.
// Double-XOR swizzle (lq ^ (r&3) ^ ((r>>2)&3)): 2-way banks = free.
// grid 512 = 2 rounds; XCD chunking wg=(bx&7)*64+(bx>>3).
// ---------------------------------------------------------------------------
__global__ __launch_bounds__(512, 2)
void gemm_qk(const bf16* __restrict__ A, const bf16* __restrict__ W,
             const float* __restrict__ bq, const float* __restrict__ bk,
             float qscale, bf16* __restrict__ Qb, bf16* __restrict__ Kb)
{
    __shared__ __attribute__((aligned(16))) bf16 lds[4][16384];  // 4 x 32 KB

    const int bx = blockIdx.x;
    const int wg = (bx & 7) * 64 + (bx >> 3);   // XCD-contiguous
    const int m0 = (wg >> 2) * 128;
    const int n0 = (wg & 3) * 384;

    const bf16* Ag = A + (long)m0 * 768;
    const bf16* Bg = W + (long)n0 * 768;

    const int tid = threadIdx.x, wv = tid >> 6, lane = tid & 63;
    const int wr = wv >> 2, wc = wv & 3;      // wave = 64(M) x 96(N)
    const int lr = lane & 15, lq = lane >> 4;

    auto stageA = [&](int h) {                // 8 chunks: 1 per wave
        const int lin = wv * 64 + lane;
        const int r = lin >> 2, pc = lin & 3;
        const int g = pc ^ (r & 3) ^ ((r >> 2) & 3);
        gload_lds16(Ag + (long)r * 768 + h * 32 + (g << 3),
                    (char*)lds[h & 3] + lin * 16);
    };
    auto stageB = [&](int h, int a) {         // 24 chunks: 3 per wave
        const int lin = (wv * 3 + a) * 64 + lane;
        const int r = lin >> 2, pc = lin & 3;
        const int g = pc ^ (r & 3) ^ ((r >> 2) & 3);
        gload_lds16(Bg + (long)r * 768 + h * 32 + (g << 3),
                    (char*)lds[h & 3] + 8192 + lin * 16);
    };
    auto rdA = [&](int h, int mf) -> v8bf {
        const int r = wr * 64 + mf * 16 + lr;
        return *(const v8bf*)(lds[h & 3] + r * 32 +
                              ((lq ^ (r & 3) ^ ((r >> 2) & 3)) << 3));
    };
    auto rdB = [&](int h, int nf) -> v8bf {
        const int r = wc * 96 + nf * 16 + lr;
        return *(const v8bf*)(lds[h & 3] + 4096 + r * 32 +
                              ((lq ^ (r & 3) ^ ((r >> 2) & 3)) << 3));
    };

    v8bf a0[4], a1[4], bL[3], bH[3];
    v4f acc[4][6] = {};
    const int NT = 12;  // 768/64

    // prologue
    stageA(0); stageB(0, 0); stageB(0, 1); stageB(0, 2);
    stageA(1); stageB(1, 0); stageB(1, 1); stageB(1, 2);
    asm volatile("s_waitcnt vmcnt(4)" ::: "memory");
    __builtin_amdgcn_s_barrier();
    #pragma unroll
    for (int i = 0; i < 4; ++i) a0[i] = rdA(0, i);
    #pragma unroll
    for (int jn = 0; jn < 3; ++jn) bL[jn] = rdB(0, jn);

    for (int t = 0; t < NT; ++t) {
        const int h0 = 2 * t, h1 = 2 * t + 1, h2 = 2 * t + 2, h3 = 2 * t + 3;
        const bool pre = (t + 1 < NT);

        // ph0: read B(h0) n3-5; stage h2.A + h2.B0; MFMA a0 x bL (s0 lo)
        #pragma unroll
        for (int jn = 0; jn < 3; ++jn) bH[jn] = rdB(h0, 3 + jn);
        if (pre) { stageA(h2); stageB(h2, 0); }
        __builtin_amdgcn_s_setprio(1);
        #pragma unroll
        for (int i = 0; i < 4; ++i)
            #pragma unroll
            for (int jn = 0; jn < 3; ++jn)
                acc[i][jn] = MFMA16(a0[i], bL[jn], acc[i][jn]);
        __builtin_amdgcn_s_setprio(0);
        asm volatile("s_waitcnt vmcnt(2)" ::: "memory");   // H(h1) landed
        __builtin_amdgcn_s_barrier();

        // ph1: read A(h1) + B(h1) n0-2; stage h2.B1 + h2.B2; MFMA a0 x bH
        #pragma unroll
        for (int i = 0; i < 4; ++i) a1[i] = rdA(h1, i);
        #pragma unroll
        for (int jn = 0; jn < 3; ++jn) bL[jn] = rdB(h1, jn);
        if (pre) { stageB(h2, 1); stageB(h2, 2); }
        __builtin_amdgcn_s_setprio(1);
        #pragma unroll
        for (int i = 0; i < 4; ++i)
            #pragma unroll
            for (int jn = 0; jn < 3; ++jn)
                acc[i][3 + jn] = MFMA16(a0[i], bH[jn], acc[i][3 + jn]);
        __builtin_amdgcn_s_setprio(0);
        asm volatile("" ::: "memory");
        __builtin_amdgcn_s_barrier();

        // ph2: read B(h1) n3-5; stage h3.A + h3.B0; MFMA a1 x bL (s1 lo)
        #pragma unroll
        for (int jn = 0; jn < 3; ++jn) bH[jn] = rdB(h1, 3 + jn);
        if (pre) { stageA(h3); stageB(h3, 0); }
        __builtin_amdgcn_s_setprio(1);
        #pragma unroll
        for (int i = 0; i < 4; ++i)
            #pragma unroll
            for (int jn = 0; jn < 3; ++jn)
                acc[i][jn] = MFMA16(a1[i], bL[jn], acc[i][jn]);
        __builtin_amdgcn_s_setprio(0);
        asm volatile("s_waitcnt vmcnt(2)" ::: "memory");   // H(h2) landed
        __builtin_amdgcn_s_barrier();

        // ph3: read A(h2) + B(h2) n0-2 (next ph0); stage h3.B1+B2; MFMA a1 x bH
        if (pre) {
            #pragma unroll
            for (int i = 0; i < 4; ++i) a0[i] = rdA(h2, i);
            #pragma unroll
            for (int jn = 0; jn < 3; ++jn) bL[jn] = rdB(h2, jn);
            stageB(h3, 1); stageB(h3, 2);
        }
        __builtin_amdgcn_s_setprio(1);
        #pragma unroll
        for (int i = 0; i < 4; ++i)
            #pragma unroll
            for (int jn = 0; jn < 3; ++jn)
                acc[i][3 + jn] = MFMA16(a1[i], bH[jn], acc[i][3 + jn]);
        __builtin_amdgcn_s_setprio(0);
        asm volatile("" ::: "memory");
        __builtin_amdgcn_s_barrier();
    }
    asm volatile("s_waitcnt vmcnt(0)" ::: "memory");

    const bool isQ = (n0 < 768);
    const float* bias = isQ ? bq : bk;
    const float sc = isQ ? qscale : 1.0f;
    bf16* C = isQ ? Qb : Kb;
    const int c0 = isQ ? n0 : n0 - 768;

    #pragma unroll
    for (int i = 0; i < 4; ++i) {
        #pragma unroll
        for (int rr = 0; rr < 4; ++rr) {
            const int row = m0 + wr * 64 + i * 16 + lq * 4 + rr;
            #pragma unroll
            for (int jn = 0; jn < 6; ++jn) {
                const int col = c0 + wc * 96 + jn * 16 + lr;
                C[(long)row * 768 + col] = (bf16)((acc[i][jn][rr] + bias[col]) * sc);
            }
        }
    }
}

// ---------------------------------------------------------------------------
// Kernel 4: E = exp(Q.K^T) + row-sum atomics into L.  R3 structure (best
// measured: 72.6us) + double-XOR swizzle fix (2-way banks = free).
// 256x256 tile, 8 waves, wave 128(M)x64(N). H-unit = A[256][32] 16KB +
// B[256][32] 16KB = 32KB, ring-4 = 128KB. 4 phases/K-tile (m-half x k-half),
// 1 barrier/phase, 32 MFMA/phase, read-ahead-one-phase, vmcnt(2) at ph0/ph2.
// grid 512: batch = bx&7 (XCD), j = bx>>3: mt=j>>3, nt=j&7.
// ---------------------------------------------------------------------------
__global__ __launch_bounds__(512, 2)
void gemm_scores(const bf16* __restrict__ Q, const bf16* __restrict__ K,
                 bf16* __restrict__ E, float* __restrict__ L)
{
    __shared__ __attribute__((aligned(16))) bf16 lds[4][16384];  // 4 x 32 KB

    const int bx = blockIdx.x;
    const int batch = bx & 7, j = bx >> 3;      // j in [0,64)
    const int m0 = (j >> 3) * 256, n0 = (j & 7) * 256;

    const bf16* Ag = Q + (long)batch * 2048 * 768 + (long)m0 * 768;
    const bf16* Bg = K + (long)batch * 2048 * 768 + (long)n0 * 768;
    bf16* C = E + (long)batch * 2048 * 2048;
    float* Lb = L + (long)batch * 2048;

    const int tid = threadIdx.x, wv = tid >> 6, lane = tid & 63;
    const int wr = wv >> 2, wc = wv & 3;        // wave = 128(M) x 64(N)
    const int lr = lane & 15, lq = lane >> 4;

    auto stageA = [&](int h, int a) {
        const int lin = (wv * 2 + a) * 64 + lane;   // 0..1023
        const int r = lin >> 2, pc = lin & 3;
        const int g = pc ^ (r & 3) ^ ((r >> 2) & 3);
        gload_lds16(Ag + (long)r * 768 + h * 32 + (g << 3),
                    (char*)lds[h & 3] + lin * 16);
    };
    auto stageB = [&](int h, int a) {
        const int lin = (wv * 2 + a) * 64 + lane;
        const int r = lin >> 2, pc = lin & 3;
        const int g = pc ^ (r & 3) ^ ((r >> 2) & 3);
        gload_lds16(Bg + (long)r * 768 + h * 32 + (g << 3),
                    (char*)lds[h & 3] + 16384 + lin * 16);
    };
    auto rdA = [&](int h, int mf) -> v8bf {
        const int r = wr * 128 + mf * 16 + lr;
        return *(const v8bf*)(lds[h & 3] + r * 32 +
                              ((lq ^ (r & 3) ^ ((r >> 2) & 3)) << 3));
    };
    auto rdB = [&](int h, int nf) -> v8bf {
        const int r = wc * 64 + nf * 16 + lr;
        return *(const v8bf*)(lds[h & 3] + 8192 + r * 32 +
                              ((lq ^ (r & 3) ^ ((r >> 2) & 3)) << 3));
    };

    v8bf a0[4], a1[4], b0[4], b1[4];
    v4f acc[8][4] = {};
    const int NT = 12;  // 768/64

    // prologue: stage H0,H1 (8 chunks/wave); retire H0; read phase-0 frags.
    stageA(0, 0); stageA(0, 1); stageB(0, 0); stageB(0, 1);
    stageA(1, 0); stageA(1, 1); stageB(1, 0); stageB(1, 1);
    asm volatile("s_waitcnt vmcnt(4)" ::: "memory");
    __builtin_amdgcn_s_barrier();
    #pragma unroll
    for (int i = 0; i < 4; ++i) a0[i] = rdA(0, i);
    #pragma unroll
    for (int jn = 0; jn < 4; ++jn) b0[jn] = rdB(0, jn);

    for (int t = 0; t < NT; ++t) {
        const int h0 = 2 * t, h1 = 2 * t + 1, h2 = 2 * t + 2, h3 = 2 * t + 3;
        const bool pre = (t + 1 < NT);

        // ph0: read A(h0) m4-7 (for ph1); stage h2.A; MFMA m0-3 x s0
        #pragma unroll
        for (int i = 0; i < 4; ++i) a1[i] = rdA(h0, 4 + i);
        if (pre) { stageA(h2, 0); stageA(h2, 1); }
        __builtin_amdgcn_s_setprio(1);
        #pragma unroll
        for (int i = 0; i < 4; ++i)
            #pragma unroll
            for (int jn = 0; jn < 4; ++jn)
                acc[i][jn] = MFMA16(a0[i], b0[jn], acc[i][jn]);
        __builtin_amdgcn_s_setprio(0);
        asm volatile("s_waitcnt vmcnt(2)" ::: "memory");   // H(h1) landed
        __builtin_amdgcn_s_barrier();

        // ph1: read A(h1) m0-3 + B(h1) (for ph2); stage h2.B; MFMA m4-7 x s0
        #pragma unroll
        for (int i = 0; i < 4; ++i) a0[i] = rdA(h1, i);
        #pragma unroll
        for (int jn = 0; jn < 4; ++jn) b1[jn] = rdB(h1, jn);
        if (pre) { stageB(h2, 0); stageB(h2, 1); }
        __builtin_amdgcn_s_setprio(1);
        #pragma unroll
        for (int i = 0; i < 4; ++i)
            #pragma unroll
            for (int jn = 0; jn < 4; ++jn)
                acc[4 + i][jn] = MFMA16(a1[i], b0[jn], acc[4 + i][jn]);
        __builtin_amdgcn_s_setprio(0);
        asm volatile("" ::: "memory");
        __builtin_amdgcn_s_barrier();

        // ph2: read A(h1) m4-7 (for ph3); stage h3.A; MFMA m0-3 x s1
        #pragma unroll
        for (int i = 0; i < 4; ++i) a1[i] = rdA(h1, 4 + i);
        if (pre) { stageA(h3, 0); stageA(h3, 1); }
        __builtin_amdgcn_s_setprio(1);
        #pragma unroll
        for (int i = 0; i < 4; ++i)
            #pragma unroll
            for (int jn = 0; jn < 4; ++jn)
                acc[i][jn] = MFMA16(a0[i], b1[jn], acc[i][jn]);
        __builtin_amdgcn_s_setprio(0);
        asm volatile("s_waitcnt vmcnt(2)" ::: "memory");   // H(h2) landed
        __builtin_amdgcn_s_barrier();

        // ph3: read A(h2) m0-3 + B(h2) (for next ph0); stage h3.B; MFMA m4-7 x s1
        if (pre) {
            #pragma unroll
            for (int i = 0; i < 4; ++i) a0[i] = rdA(h2, i);
            #pragma unroll
            for (int jn = 0; jn < 4; ++jn) b0[jn] = rdB(h2, jn);
            stageB(h3, 0); stageB(h3, 1);
        }
        __builtin_amdgcn_s_setprio(1);
        #pragma unroll
        for (int i = 0; i < 4; ++i)
            #pragma unroll
            for (int jn = 0; jn < 4; ++jn)
                acc[4 + i][jn] = MFMA16(a1[i], b1[jn], acc[4 + i][jn]);
        __builtin_amdgcn_s_setprio(0);
        asm volatile("" ::: "memory");
        __builtin_amdgcn_s_barrier();
    }

    // epilogue: exp + 16-lane row-sum reduce + atomics + bf16 store
    #pragma unroll
    for (int i = 0; i < 8; ++i) {
        #pragma unroll
        for (int rr = 0; rr < 4; ++rr) {
            const int row = m0 + wr * 128 + i * 16 + lq * 4 + rr;
            float e[4], rs = 0.f;
            #pragma unroll
            for (int jn = 0; jn < 4; ++jn) {
                e[jn] = __expf(acc[i][jn][rr]);
                rs += e[jn];
            }
            #pragma unroll
            for (int off = 1; off < 16; off <<= 1) rs += __shfl_xor(rs, off);
            if (lr == 0) atomicAdd(&Lb[row], rs);
            #pragma unroll
            for (int jn = 0; jn < 4; ++jn) {
                const int col = n0 + wc * 64 + jn * 16 + lr;
                C[(long)row * 2048 + col] = (bf16)e[jn];
            }
        }
    }
}

// ---------------------------------------------------------------------------
// Kernel 5: Out = (E.V^T)/L + Xres. R3 structure + double-XOR swizzle.
// 128(M)x384(N) tile, 8 waves, wave 64x96. H = A[128][32] 8KB +
// B[384][32] 24KB = 32KB, ring-4 = 128KB. Phases by (k-half, n-half):
// reads 7/3/7/3 vs 12 MFMA, read-ahead + counted vmcnt(2).
// grid 256 = 1 block/CU: batch = bx&7, j = bx>>3: mt=j>>1, nt=j&1.
// ---------------------------------------------------------------------------
__global__ __launch_bounds__(512, 2)
void gemm_pv(const bf16* __restrict__ P, const bf16* __restrict__ VT,
             const float* __restrict__ L, const float* __restrict__ Xres,
             float* __restrict__ Out)
{
    __shared__ __attribute__((aligned(16))) bf16 lds[4][16384];  // 4 x 32 KB

    const int bx = blockIdx.x;
    const int batch = bx & 7, j = bx >> 3;   // j in [0,32)
    const int m0 = (j >> 1) * 128;
    const int n0 = (j & 1) * 384;

    const bf16* Ag = P  + (long)batch * 2048 * 2048 + (long)m0 * 2048;
    const bf16* Bg = VT + (long)batch * 768 * 2048  + (long)n0 * 2048;
    const float* Lb = L + (long)batch * 2048;
    const float* Xr = Xres + (long)batch * 2048 * 768;
    float* O = Out + (long)batch * 2048 * 768;

    const int tid = threadIdx.x, wv = tid >> 6, lane = tid & 63;
    const int wr = wv >> 2, wc = wv & 3;      // wave = 64(M) x 96(N)
    const int lr = lane & 15, lq = lane >> 4;

    auto stageA = [&](int h) {                // 8 chunks: 1 per wave
        const int lin = wv * 64 + lane;
        const int r = lin >> 2, pc = lin & 3;
        const int g = pc ^ (r & 3) ^ ((r >> 2) & 3);
        gload_lds16(Ag + (long)r * 2048 + h * 32 + (g << 3),
                    (char*)lds[h & 3] + lin * 16);
    };
    auto stageB = [&](int h, int a) {         // 24 chunks: 3 per wave
        const int lin = (wv * 3 + a) * 64 + lane;
        const int r = lin >> 2, pc = lin & 3;
        const int g = pc ^ (r & 3) ^ ((r >> 2) & 3);
        gload_lds16(Bg + (long)r * 2048 + h * 32 + (g << 3),
                    (char*)lds[h & 3] + 8192 + lin * 16);
    };
    auto rdA = [&](int h, int mf) -> v8bf {
        const int r = wr * 64 + mf * 16 + lr;
        return *(const v8bf*)(lds[h & 3] + r * 32 +
                              ((lq ^ (r & 3) ^ ((r >> 2) & 3)) << 3));
    };
    auto rdB = [&](int h, int nf) -> v8bf {
        const int r = wc * 96 + nf * 16 + lr;
        return *(const v8bf*)(lds[h & 3] + 4096 + r * 32 +
                              ((lq ^ (r & 3) ^ ((r >> 2) & 3)) << 3));
    };

    v8bf a0[4], a1[4], bL[3], bH[3];
    v4f acc[4][6] = {};
    const int NT = 32;  // 2048/64

    // prologue
    stageA(0); stageB(0, 0); stageB(0, 1); stageB(0, 2);
    stageA(1); stageB(1, 0); stageB(1, 1); stageB(1, 2);
    asm volatile("s_waitcnt vmcnt(4)" ::: "memory");
    __builtin_amdgcn_s_barrier();
    #pragma unroll
    for (int i = 0; i < 4; ++i) a0[i] = rdA(0, i);
    #pragma unroll
    for (int jn = 0; jn < 3; ++jn) bL[jn] = rdB(0, jn);

    for (int t = 0; t < NT; ++t) {
        const int h0 = 2 * t, h1 = 2 * t + 1, h2 = 2 * t + 2, h3 = 2 * t + 3;
        const bool pre = (t + 1 < NT);

        // ph0: read B(h0) n3-5; stage h2.A + h2.B0; MFMA a0 x bL (s0 lo)
        #pragma unroll
        for (int jn = 0; jn < 3; ++jn) bH[jn] = rdB(h0, 3 + jn);
        if (pre) { stageA(h2); stageB(h2, 0); }
        __builtin_amdgcn_s_setprio(1);
        #pragma unroll
        for (int i = 0; i < 4; ++i)
            #pragma unroll
            for (int jn = 0; jn < 3; ++jn)
                acc[i][jn] = MFMA16(a0[i], bL[jn], acc[i][jn]);
        __builtin_amdgcn_s_setprio(0);
        asm volatile("s_waitcnt vmcnt(2)" ::: "memory");   // H(h1) landed
        __builtin_amdgcn_s_barrier();

        // ph1: read A(h1) + B(h1) n0-2; stage h2.B1 + h2.B2; MFMA a0 x bH
        #pragma unroll
        for (int i = 0; i < 4; ++i) a1[i] = rdA(h1, i);
        #pragma unroll
        for (int jn = 0; jn < 3; ++jn) bL[jn] = rdB(h1, jn);
        if (pre) { stageB(h2, 1); stageB(h2, 2); }
        __builtin_amdgcn_s_setprio(1);
        #pragma unroll
        for (int i = 0; i < 4; ++i)
            #pragma unroll
            for (int jn = 0; jn < 3; ++jn)
                acc[i][3 + jn] = MFMA16(a0[i], bH[jn], acc[i][3 + jn]);
        __builtin_amdgcn_s_setprio(0);
        asm volatile("" ::: "memory");
        __builtin_amdgcn_s_barrier();

        // ph2: read B(h1) n3-5; stage h3.A + h3.B0; MFMA a1 x bL (s1 lo)
        #pragma unroll
        for (int jn = 0; jn < 3; ++jn) bH[jn] = rdB(h1, 3 + jn);
        if (pre) { stageA(h3); stageB(h3, 0); }
        __builtin_amdgcn_s_setprio(1);
        #pragma unroll
        for (int i = 0; i < 4; ++i)
            #pragma unroll
            for (int jn = 0; jn < 3; ++jn)
                acc[i][jn] = MFMA16(a1[i], bL[jn], acc[i][jn]);
        __builtin_amdgcn_s_setprio(0);
        asm volatile("s_waitcnt vmcnt(2)" ::: "memory");   // H(h2) landed
        __builtin_amdgcn_s_barrier();

        // ph3: read A(h2) + B(h2) n0-2 (next ph0); stage h3.B1+B2; MFMA a1 x bH
        if (pre) {
            #pragma unroll
            for (int i = 0; i < 4; ++i) a0[i] = rdA(h2, i);
            #pragma unroll
            for (int jn = 0; jn < 3; ++jn) bL[jn] = rdB(h2, jn);
            stageB(h3, 1); stageB(h3, 2);
        }
        __builtin_amdgcn_s_setprio(1);
        #pragma unroll
        for (int i = 0; i < 4; ++i)
            #pragma unroll
            for (int jn = 0; jn < 3; ++jn)
                acc[i][3 + jn] = MFMA16(a1[i], bH[jn], acc[i][3 + jn]);
        __builtin_amdgcn_s_setprio(0);
        asm volatile("" ::: "memory");
        __builtin_amdgcn_s_barrier();
    }

    // epilogue: O = acc/L[row] + Xres
    #pragma unroll
    for (int i = 0; i < 4; ++i) {
        #pragma unroll
        for (int rr = 0; rr < 4; ++rr) {
            const int row = m0 + wr * 64 + i * 16 + lq * 4 + rr;
            const float invL = 1.0f / Lb[row];
            #pragma unroll
            for (int jn = 0; jn < 6; ++jn) {
                const int col = n0 + wc * 96 + jn * 16 + lr;
                const long idx = (long)row * 768 + col;
                O[idx] = acc[i][jn][rr] * invL + Xr[idx];
            }
        }
    }
}

// ---------------------------------------------------------------------------
extern "C" void kernel_launch(void* const* d_in, const int* in_sizes, int n_in,
                              void* d_out, int out_size, void* d_ws, size_t ws_size,
                              hipStream_t stream)
{
    const float* x    = (const float*)d_in[0];
    const float* ln_g = (const float*)d_in[1];
    const float* ln_b = (const float*)d_in[2];
    const float* Wq   = (const float*)d_in[3];
    const float* bq   = (const float*)d_in[4];
    const float* Wk   = (const float*)d_in[5];
    const float* bk   = (const float*)d_in[6];
    float* out = (float*)d_out;

    const long R = 8L * 2048;  // 16384 rows
    char* ws = (char*)d_ws;
    size_t off = 0;
    auto take = [&](size_t bytes) -> char* {
        char* p = ws + off;
        off += (bytes + 255) & ~(size_t)255;
        return p;
    };
    bf16*  xn   = (bf16*)take(R * 768 * 2);   // reused as xvT after projection
    bf16*  xv   = (bf16*)take(R * 768 * 2);
    bf16*  Qb   = (bf16*)take(R * 768 * 2);
    bf16*  Kb   = (bf16*)take(R * 768 * 2);
    bf16*  Wcat = (bf16*)take(1536L * 768 * 2);
    float* Lrow = (float*)take(R * 4);        // softmax denominators
    bf16*  Sc   = (bf16*)take(8L * 2048 * 2048 * 2);  // E = exp(scores)

    ln_cast<<<R, 256, 0, stream>>>(x, ln_g, ln_b, xn, xv, Lrow);
    cvt_w<<<dim3(576, 2), 256, 0, stream>>>(Wq, Wk, Wcat);

    const float qscale = 0.036084391824351615f;  // 1/sqrt(768), folded into Q
    gemm_qk<<<512, 512, 0, stream>>>(xn, Wcat, bq, bk, qscale, Qb, Kb);

    // xn dead now; reuse its buffer for xvT [8][768][2048]
    bf16* xvT = xn;
    transpose_bf<<<dim3(32, 12, 8), 256, 0, stream>>>(xv, xvT);

    gemm_scores<<<512, 512, 0, stream>>>(Qb, Kb, Sc, Lrow);
    gemm_pv<<<256, 512, 0, stream>>>(Sc, xvT, Lrow, x, out);
}